// Round 11
// baseline (22.806 us; speedup 1.0000x reference)
//
#include <hip/hip_runtime.h>
#include <hip/hip_cooperative_groups.h>

namespace cg = cooperative_groups;

// Problem constants (fixed by reference setup_inputs)
constexpr int B_ = 32;
constexpr int S_ = 4096;
constexpr int D_ = 256;
constexpr int PAIRS_PER_BATCH = S_ - 1;                                   // 4095
constexpr int CHUNK = 16;                                                 // pairs per chunk
constexpr int CHUNKS_PER_BATCH = (PAIRS_PER_BATCH + CHUNK - 1) / CHUNK;   // 256
constexpr int NCHUNKS = B_ * CHUNKS_PER_BATCH;                            // 8192
constexpr int BLOCK = 512;                                                // 8 waves/block
constexpr int WAVES_PER_BLOCK = BLOCK / 64;                               // 8
constexpr int NBLOCKS = 1024;                                             // 4 blocks/CU
// 1024 blocks x 8 waves = 8192 waves = exactly 1 chunk per wave.
// 4 blocks/CU x 8 waves = 32 waves/CU = full occupancy (needs VGPR <= 64).

// One chunk (16 consecutive pairs of one batch row): ballot mask from one
// coalesced label read; row loads gated by the mask (only rows adjacent to
// a masked pair); per-pair diff + 64-lane butterfly + sqrt. Wave-uniform
// branches throughout. (R2-proven body, measured 40 VGPR.)
__device__ __forceinline__ float chunk_sum(const float* __restrict__ emb,
                                           const int* __restrict__ lab,
                                           int chunk, int lane) {
  const int b = chunk / CHUNKS_PER_BATCH;
  const int c = chunk % CHUNKS_PER_BATCH;
  const int p0 = c * CHUNK;
  const int npairs = min(CHUNK, PAIRS_PER_BATCH - p0);   // 16 (15 for last chunk)

  const float4* __restrict__ rows =
      reinterpret_cast<const float4*>(emb + (size_t)b * S_ * D_);
  const int* __restrict__ lb = lab + b * S_;

  int lv = 0;
  if (lane <= npairs) lv = lb[p0 + lane];
  const int nl = __shfl_down(lv, 1, 64);
  const bool m = (lane < npairs) && (lv != 0) && (lv == nl);
  const unsigned long long mask = __ballot(m);
  if (mask == 0ULL) return 0.0f;

  const unsigned long long rowmask = mask | (mask << 1);

  float4 r[CHUNK + 1];
  #pragma unroll
  for (int i = 0; i <= CHUNK; ++i) {
    if ((rowmask >> i) & 1ULL) {
      r[i] = rows[(size_t)(p0 + i) * (D_ / 4) + lane];
    }
  }

  float wsum = 0.0f;
  #pragma unroll
  for (int i = 0; i < CHUNK; ++i) {
    if ((mask >> i) & 1ULL) {
      const float dx = r[i].x - r[i + 1].x;
      const float dy = r[i].y - r[i + 1].y;
      const float dz = r[i].z - r[i + 1].z;
      const float dw = r[i].w - r[i + 1].w;
      float s = dx * dx + dy * dy + dz * dz + dw * dw;
      #pragma unroll
      for (int xm = 1; xm < 64; xm <<= 1) s += __shfl_xor(s, xm, 64);
      wsum += sqrtf(s);
    }
  }
  return wsum;
}

// Each wave handles exactly one chunk; 8 wave partials -> block partial.
__device__ __forceinline__ void block_partial(const float* __restrict__ emb,
                                              const int* __restrict__ lab,
                                              float* __restrict__ partial,
                                              float* __restrict__ lds) {
  const int tid = threadIdx.x;
  const int lane = tid & 63;
  const int w = tid >> 6;
  const int wave = blockIdx.x * WAVES_PER_BLOCK + w;   // 0..8191 == chunk id

  const float wsum = chunk_sum(emb, lab, wave, lane);

  if (lane == 0) lds[w] = wsum;
  __syncthreads();
  if (tid == 0) {
    float bsum = 0.0f;
    #pragma unroll
    for (int i = 0; i < WAVES_PER_BLOCK; ++i) bsum += lds[i];
    partial[blockIdx.x] = bsum;
  }
}

// Cooperative single-node version: grid.sync then block 0 reduces.
// __launch_bounds__(512, 8): 8 waves/EU -> VGPR cap 64 (body is 40) ->
// 4 blocks/CU -> all 1024 blocks co-resident at full occupancy.
__global__ __launch_bounds__(BLOCK, 8) void ccl_coop_kernel(
    const float* __restrict__ emb, const int* __restrict__ lab,
    float* __restrict__ out, float* __restrict__ partial) {
  __shared__ float lds[WAVES_PER_BLOCK];
  block_partial(emb, lab, partial, lds);

  cg::this_grid().sync();

  if (blockIdx.x != 0) return;
  const int tid = threadIdx.x;
  const int lane = tid & 63;
  const int w = tid >> 6;
  float s = 0.0f;
  for (int i = tid; i < NBLOCKS; i += BLOCK) s += partial[i];   // 2 each, fixed order
  #pragma unroll
  for (int xm = 1; xm < 64; xm <<= 1) s += __shfl_xor(s, xm, 64);
  __shared__ float lds2[WAVES_PER_BLOCK];
  if (lane == 0) lds2[w] = s;
  __syncthreads();
  if (tid == 0) {
    float t = 0.0f;
    #pragma unroll
    for (int i = 0; i < WAVES_PER_BLOCK; ++i) t += lds2[i];
    out[0] = t / (float)((long long)B_ * S_);
  }
}

// Fallback two-kernel version (proven structure).
__global__ __launch_bounds__(BLOCK, 8) void ccl_body_kernel(
    const float* __restrict__ emb, const int* __restrict__ lab,
    float* __restrict__ partial) {
  __shared__ float lds[WAVES_PER_BLOCK];
  block_partial(emb, lab, partial, lds);
}

__global__ __launch_bounds__(BLOCK) void ccl_reduce_kernel(
    const float* __restrict__ partial, float* __restrict__ out) {
  const int tid = threadIdx.x;
  const int lane = tid & 63;
  const int w = tid >> 6;
  float s = 0.0f;
  for (int i = tid; i < NBLOCKS; i += BLOCK) s += partial[i];
  #pragma unroll
  for (int xm = 1; xm < 64; xm <<= 1) s += __shfl_xor(s, xm, 64);
  __shared__ float lds2[WAVES_PER_BLOCK];
  if (lane == 0) lds2[w] = s;
  __syncthreads();
  if (tid == 0) {
    float t = 0.0f;
    #pragma unroll
    for (int i = 0; i < WAVES_PER_BLOCK; ++i) t += lds2[i];
    out[0] = t / (float)((long long)B_ * S_);
  }
}

extern "C" void kernel_launch(void* const* d_in, const int* in_sizes, int n_in,
                              void* d_out, int out_size, void* d_ws, size_t ws_size,
                              hipStream_t stream) {
  const float* emb = (const float*)d_in[0];
  const int* lab = (const int*)d_in[1];
  float* out = (float*)d_out;
  float* partial = (float*)d_ws;   // NBLOCKS floats = 4 KiB

  // Host-side, capture-safe, deterministic gating: only take the cooperative
  // path if the runtime confirms full co-residency for this grid.
  int dev = 0;
  (void)hipGetDevice(&dev);
  int coop = 0;
  (void)hipDeviceGetAttribute(&coop, hipDeviceAttributeCooperativeLaunch, dev);
  int ncu = 0;
  (void)hipDeviceGetAttribute(&ncu, hipDeviceAttributeMultiprocessorCount, dev);
  int maxb = 0;
  (void)hipOccupancyMaxActiveBlocksPerMultiprocessor(
      &maxb, (const void*)ccl_coop_kernel, BLOCK, 0);

  if (coop && (long long)maxb * ncu >= NBLOCKS) {
    void* args[4] = {(void*)&emb, (void*)&lab, (void*)&out, (void*)&partial};
    hipError_t e = hipLaunchCooperativeKernel((const void*)ccl_coop_kernel,
                                              dim3(NBLOCKS), dim3(BLOCK), args,
                                              0, stream);
    if (e == hipSuccess) return;
    // else fall through to the two-kernel path
  }

  ccl_body_kernel<<<NBLOCKS, BLOCK, 0, stream>>>(emb, lab, partial);
  ccl_reduce_kernel<<<1, BLOCK, 0, stream>>>(partial, out);
}

// Round 12
// 16.045 us; speedup vs baseline: 1.4214x; 1.4214x over previous
//
#include <hip/hip_runtime.h>
#include <hip/hip_cooperative_groups.h>

namespace cg = cooperative_groups;

// Problem constants (fixed by reference setup_inputs)
constexpr int B_ = 32;
constexpr int S_ = 4096;
constexpr int D_ = 256;
constexpr int PAIRS_PER_BATCH = S_ - 1;                                   // 4095
constexpr int CHUNK = 16;                                                 // pairs per chunk
constexpr int CHUNKS_PER_BATCH = (PAIRS_PER_BATCH + CHUNK - 1) / CHUNK;   // 256
constexpr int NCHUNKS = B_ * CHUNKS_PER_BATCH;                            // 8192
constexpr int BLOCK = 256;
constexpr int WAVES_PER_BLOCK = BLOCK / 64;                               // 4
constexpr int NBLOCKS = 1024;                                             // R9-proven optimum
constexpr int NWAVES = NBLOCKS * WAVES_PER_BLOCK;                         // 4096 -> 2 chunks/wave

// One chunk (16 consecutive pairs of one batch row).
// Loads are UNCONDITIONAL with predicated addresses: unneeded slots alias
// the chunk's first needed row (L1 hit, no extra HBM traffic; ctz <= 15 so
// always in-bounds; for the short last chunk rowmask bit 16 is 0 so the
// real address is always valid). All 17 float4 land in DISTINCT registers
// with no intervening s_waitcnt -> ~1 exposed L2/L3 round trip per chunk
// instead of ~17 serialized ones (R9 showed VGPR=44 => compiler recycled
// registers and serialized). sched_barrier(0) keeps loads above compute.
__device__ __forceinline__ float chunk_sum(const float* __restrict__ emb,
                                           const int* __restrict__ lab,
                                           int chunk, int lane) {
  const int b = chunk / CHUNKS_PER_BATCH;
  const int c = chunk % CHUNKS_PER_BATCH;
  const int p0 = c * CHUNK;
  const int npairs = min(CHUNK, PAIRS_PER_BATCH - p0);   // 16 (15 for last chunk)

  const float4* __restrict__ rows =
      reinterpret_cast<const float4*>(emb + (size_t)b * S_ * D_);
  const int* __restrict__ lb = lab + b * S_;

  int lv = 0;
  if (lane <= npairs) lv = lb[p0 + lane];
  const int nl = __shfl_down(lv, 1, 64);
  const bool m = (lane < npairs) && (lv != 0) && (lv == nl);
  const unsigned long long mask = __ballot(m);
  if (mask == 0ULL) return 0.0f;     // wave-uniform; ~36% of chunks

  const unsigned long long rowmask = mask | (mask << 1);
  const int firstrow = (int)__builtin_ctzll(rowmask);    // <= 15

  float4 r[CHUNK + 1];
  #pragma unroll
  for (int i = 0; i <= CHUNK; ++i) {
    const int row = ((rowmask >> i) & 1ULL) ? (p0 + i) : (p0 + firstrow);
    r[i] = rows[(size_t)row * (D_ / 4) + lane];
  }
  __builtin_amdgcn_sched_barrier(0);   // all loads issued before any compute

  float wsum = 0.0f;
  #pragma unroll
  for (int i = 0; i < CHUNK; ++i) {
    if ((mask >> i) & 1ULL) {
      const float dx = r[i].x - r[i + 1].x;
      const float dy = r[i].y - r[i + 1].y;
      const float dz = r[i].z - r[i + 1].z;
      const float dw = r[i].w - r[i + 1].w;
      float s = dx * dx + dy * dy + dz * dz + dw * dw;
      #pragma unroll
      for (int xm = 1; xm < 64; xm <<= 1) s += __shfl_xor(s, xm, 64);
      wsum += sqrtf(s);
    }
  }
  return wsum;
}

// Each wave: 2 chunks (serial); 4 wave partials -> block partial.
__device__ __forceinline__ void block_partial(const float* __restrict__ emb,
                                              const int* __restrict__ lab,
                                              float* __restrict__ partial) {
  const int tid = threadIdx.x;
  const int lane = tid & 63;
  const int w = tid >> 6;
  const int wave = blockIdx.x * WAVES_PER_BLOCK + w;   // 0..4095

  float wsum = chunk_sum(emb, lab, wave, lane);
  wsum += chunk_sum(emb, lab, wave + NWAVES, lane);

  __shared__ float lds[WAVES_PER_BLOCK];
  if (lane == 0) lds[w] = wsum;
  __syncthreads();
  if (tid == 0) {
    partial[blockIdx.x] = ((lds[0] + lds[1]) + lds[2]) + lds[3];
  }
}

// Cooperative single-node version (R9 topology): grid.sync, block 0 reduces.
// __launch_bounds__(256,4): VGPR cap 128 -> the 17 in-flight float4 (~110
// live VGPR) fit without spill; 4 blocks/CU co-residency, ample for 1024.
__global__ __launch_bounds__(BLOCK, 4) void ccl_coop_kernel(
    const float* __restrict__ emb, const int* __restrict__ lab,
    float* __restrict__ out, float* __restrict__ partial) {
  block_partial(emb, lab, partial);

  cg::this_grid().sync();

  if (blockIdx.x != 0) return;
  const int tid = threadIdx.x;
  const int lane = tid & 63;
  const int w = tid >> 6;
  float s = 0.0f;
  for (int i = tid; i < NBLOCKS; i += BLOCK) s += partial[i];   // 4 each, fixed order
  #pragma unroll
  for (int xm = 1; xm < 64; xm <<= 1) s += __shfl_xor(s, xm, 64);
  __shared__ float lds2[WAVES_PER_BLOCK];
  if (lane == 0) lds2[w] = s;
  __syncthreads();
  if (tid == 0) {
    out[0] = (((lds2[0] + lds2[1]) + lds2[2]) + lds2[3]) /
             (float)((long long)B_ * S_);
  }
}

// Fallback two-kernel version (proven structure).
__global__ __launch_bounds__(BLOCK, 4) void ccl_body_kernel(
    const float* __restrict__ emb, const int* __restrict__ lab,
    float* __restrict__ partial) {
  block_partial(emb, lab, partial);
}

__global__ __launch_bounds__(BLOCK) void ccl_reduce_kernel(
    const float* __restrict__ partial, float* __restrict__ out) {
  const int tid = threadIdx.x;
  const int lane = tid & 63;
  const int w = tid >> 6;
  float s = 0.0f;
  for (int i = tid; i < NBLOCKS; i += BLOCK) s += partial[i];
  #pragma unroll
  for (int xm = 1; xm < 64; xm <<= 1) s += __shfl_xor(s, xm, 64);
  __shared__ float lds2[WAVES_PER_BLOCK];
  if (lane == 0) lds2[w] = s;
  __syncthreads();
  if (tid == 0) {
    out[0] = (((lds2[0] + lds2[1]) + lds2[2]) + lds2[3]) /
             (float)((long long)B_ * S_);
  }
}

extern "C" void kernel_launch(void* const* d_in, const int* in_sizes, int n_in,
                              void* d_out, int out_size, void* d_ws, size_t ws_size,
                              hipStream_t stream) {
  const float* emb = (const float*)d_in[0];
  const int* lab = (const int*)d_in[1];
  float* out = (float*)d_out;
  float* partial = (float*)d_ws;   // NBLOCKS floats = 4 KiB

  // Host-side, capture-safe, deterministic gating: only take the cooperative
  // path if the runtime confirms full co-residency for this grid.
  int dev = 0;
  (void)hipGetDevice(&dev);
  int coop = 0;
  (void)hipDeviceGetAttribute(&coop, hipDeviceAttributeCooperativeLaunch, dev);
  int ncu = 0;
  (void)hipDeviceGetAttribute(&ncu, hipDeviceAttributeMultiprocessorCount, dev);
  int maxb = 0;
  (void)hipOccupancyMaxActiveBlocksPerMultiprocessor(
      &maxb, (const void*)ccl_coop_kernel, BLOCK, 0);

  if (coop && (long long)maxb * ncu >= NBLOCKS) {
    void* args[4] = {(void*)&emb, (void*)&lab, (void*)&out, (void*)&partial};
    hipError_t e = hipLaunchCooperativeKernel((const void*)ccl_coop_kernel,
                                              dim3(NBLOCKS), dim3(BLOCK), args,
                                              0, stream);
    if (e == hipSuccess) return;
    // else fall through to the two-kernel path
  }

  ccl_body_kernel<<<NBLOCKS, BLOCK, 0, stream>>>(emb, lab, partial);
  ccl_reduce_kernel<<<1, BLOCK, 0, stream>>>(partial, out);
}

// Round 13
// 15.789 us; speedup vs baseline: 1.4445x; 1.0162x over previous
//
#include <hip/hip_runtime.h>
#include <hip/hip_cooperative_groups.h>

namespace cg = cooperative_groups;

// Problem constants (fixed by reference setup_inputs)
constexpr int B_ = 32;
constexpr int S_ = 4096;
constexpr int D_ = 256;
constexpr int PAIRS_PER_BATCH = S_ - 1;                                   // 4095
constexpr int CHUNK = 16;                                                 // pairs per chunk
constexpr int CHUNKS_PER_BATCH = (PAIRS_PER_BATCH + CHUNK - 1) / CHUNK;   // 256
constexpr int NCHUNKS = B_ * CHUNKS_PER_BATCH;                            // 8192
constexpr int BLOCK = 1024;                                               // 16 waves/block
constexpr int WAVES_PER_BLOCK = BLOCK / 64;                               // 16
constexpr int NBLOCKS = 256;                                              // 1 block/CU exactly
constexpr int NWAVES = NBLOCKS * WAVES_PER_BLOCK;                         // 4096 -> 2 chunks/wave
// Same wave-level config as the 15.6us R9 optimum (4096 waves, 2 chunks each,
// 16 waves/CU) but 4x fewer grid.sync arrivals (256 vs 1024 blocks).

// One chunk (16 consecutive pairs of one batch row): ballot mask from one
// coalesced label read; row loads gated by the mask; per-pair diff +
// 64-lane butterfly + sqrt. Wave-uniform branches. (R9-proven body.)
__device__ __forceinline__ float chunk_sum(const float* __restrict__ emb,
                                           const int* __restrict__ lab,
                                           int chunk, int lane) {
  const int b = chunk / CHUNKS_PER_BATCH;
  const int c = chunk % CHUNKS_PER_BATCH;
  const int p0 = c * CHUNK;
  const int npairs = min(CHUNK, PAIRS_PER_BATCH - p0);   // 16 (15 for last chunk)

  const float4* __restrict__ rows =
      reinterpret_cast<const float4*>(emb + (size_t)b * S_ * D_);
  const int* __restrict__ lb = lab + b * S_;

  int lv = 0;
  if (lane <= npairs) lv = lb[p0 + lane];
  const int nl = __shfl_down(lv, 1, 64);
  const bool m = (lane < npairs) && (lv != 0) && (lv == nl);
  const unsigned long long mask = __ballot(m);
  if (mask == 0ULL) return 0.0f;     // wave-uniform; ~36% of chunks

  const unsigned long long rowmask = mask | (mask << 1);

  float4 r[CHUNK + 1];
  #pragma unroll
  for (int i = 0; i <= CHUNK; ++i) {
    if ((rowmask >> i) & 1ULL) {
      r[i] = rows[(size_t)(p0 + i) * (D_ / 4) + lane];
    }
  }

  float wsum = 0.0f;
  #pragma unroll
  for (int i = 0; i < CHUNK; ++i) {
    if ((mask >> i) & 1ULL) {
      const float dx = r[i].x - r[i + 1].x;
      const float dy = r[i].y - r[i + 1].y;
      const float dz = r[i].z - r[i + 1].z;
      const float dw = r[i].w - r[i + 1].w;
      float s = dx * dx + dy * dy + dz * dz + dw * dw;
      #pragma unroll
      for (int xm = 1; xm < 64; xm <<= 1) s += __shfl_xor(s, xm, 64);
      wsum += sqrtf(s);
    }
  }
  return wsum;
}

// Each wave: 2 chunks (serial); 16 wave partials -> block partial.
__device__ __forceinline__ void block_partial(const float* __restrict__ emb,
                                              const int* __restrict__ lab,
                                              float* __restrict__ partial) {
  const int tid = threadIdx.x;
  const int lane = tid & 63;
  const int w = tid >> 6;
  const int wave = blockIdx.x * WAVES_PER_BLOCK + w;   // 0..4095

  float wsum = chunk_sum(emb, lab, wave, lane);
  wsum += chunk_sum(emb, lab, wave + NWAVES, lane);

  __shared__ float lds[WAVES_PER_BLOCK];
  if (lane == 0) lds[w] = wsum;
  __syncthreads();
  if (tid == 0) {
    float bsum = 0.0f;
    #pragma unroll
    for (int i = 0; i < WAVES_PER_BLOCK; ++i) bsum += lds[i];
    partial[blockIdx.x] = bsum;
  }
}

// Cooperative single-node version: grid.sync (256 arrivals), block 0 reduces.
// __launch_bounds__(1024, 4): 4 waves/EU -> VGPR cap 128 (body ~44) ->
// 1 block/CU; 256 blocks on 256 CUs.
__global__ __launch_bounds__(BLOCK, 4) void ccl_coop_kernel(
    const float* __restrict__ emb, const int* __restrict__ lab,
    float* __restrict__ out, float* __restrict__ partial) {
  block_partial(emb, lab, partial);

  cg::this_grid().sync();

  if (blockIdx.x != 0) return;
  const int tid = threadIdx.x;
  const int lane = tid & 63;
  const int w = tid >> 6;
  float s = (tid < NBLOCKS) ? partial[tid] : 0.0f;   // one partial per thread
  #pragma unroll
  for (int xm = 1; xm < 64; xm <<= 1) s += __shfl_xor(s, xm, 64);
  __shared__ float lds2[WAVES_PER_BLOCK];
  if (lane == 0) lds2[w] = s;
  __syncthreads();
  if (tid == 0) {
    float t = 0.0f;
    #pragma unroll
    for (int i = 0; i < WAVES_PER_BLOCK; ++i) t += lds2[i];   // waves 4..15 contribute 0
    out[0] = t / (float)((long long)B_ * S_);
  }
}

// Fallback two-kernel version (proven structure).
__global__ __launch_bounds__(BLOCK, 4) void ccl_body_kernel(
    const float* __restrict__ emb, const int* __restrict__ lab,
    float* __restrict__ partial) {
  block_partial(emb, lab, partial);
}

__global__ __launch_bounds__(256) void ccl_reduce_kernel(
    const float* __restrict__ partial, float* __restrict__ out) {
  const int tid = threadIdx.x;
  const int lane = tid & 63;
  const int w = tid >> 6;
  float s = (tid < NBLOCKS) ? partial[tid] : 0.0f;
  #pragma unroll
  for (int xm = 1; xm < 64; xm <<= 1) s += __shfl_xor(s, xm, 64);
  __shared__ float lds2[4];
  if (lane == 0) lds2[w] = s;
  __syncthreads();
  if (tid == 0) {
    out[0] = (((lds2[0] + lds2[1]) + lds2[2]) + lds2[3]) /
             (float)((long long)B_ * S_);
  }
}

extern "C" void kernel_launch(void* const* d_in, const int* in_sizes, int n_in,
                              void* d_out, int out_size, void* d_ws, size_t ws_size,
                              hipStream_t stream) {
  const float* emb = (const float*)d_in[0];
  const int* lab = (const int*)d_in[1];
  float* out = (float*)d_out;
  float* partial = (float*)d_ws;   // NBLOCKS floats = 1 KiB

  // Host-side, capture-safe, deterministic gating: only take the cooperative
  // path if the runtime confirms full co-residency for this grid.
  int dev = 0;
  (void)hipGetDevice(&dev);
  int coop = 0;
  (void)hipDeviceGetAttribute(&coop, hipDeviceAttributeCooperativeLaunch, dev);
  int ncu = 0;
  (void)hipDeviceGetAttribute(&ncu, hipDeviceAttributeMultiprocessorCount, dev);
  int maxb = 0;
  (void)hipOccupancyMaxActiveBlocksPerMultiprocessor(
      &maxb, (const void*)ccl_coop_kernel, BLOCK, 0);

  if (coop && (long long)maxb * ncu >= NBLOCKS) {
    void* args[4] = {(void*)&emb, (void*)&lab, (void*)&out, (void*)&partial};
    hipError_t e = hipLaunchCooperativeKernel((const void*)ccl_coop_kernel,
                                              dim3(NBLOCKS), dim3(BLOCK), args,
                                              0, stream);
    if (e == hipSuccess) return;
    // else fall through to the two-kernel path
  }

  ccl_body_kernel<<<NBLOCKS, BLOCK, 0, stream>>>(emb, lab, partial);
  ccl_reduce_kernel<<<1, 256, 0, stream>>>(partial, out);
}